// Round 8
// baseline (124.405 us; speedup 1.0000x reference)
//
#include <hip/hip_runtime.h>

// Helmholtz on MI355X — established harness world (rounds 0-7):
//   n_in==3, all float32 planes of 8,388,608 elements:
//     d_in[0] = x (real part of complex64 input; harness drops imag)
//     d_in[1] = kappa
//     d_in[2] = gamma (dead: only affects the dropped imaginary output)
//   d_out = 8,388,608 floats: out = lap(x)/h^2 - OMEGA^2*kappa^2*x
// B=8 images of 1024x1024, h=1/1024.
//
// Round 7 post-mortem: 3 structurally different kernels all ~28 us (~3.4 TB/s)
// while fills run 6.5 TB/s. Theory: full-width row-band blocks + round-robin
// workgroup->XCD dispatch puts vertically adjacent bands on different XCDs, so
// every x row is fetched by ~3 non-coherent L2s (~160 MiB effective traffic).
// This round: XCD-slab swizzle — XCD k owns image k (rows 1024k..1024k+1023),
// halos reuse within one L2, traffic -> ~96 MiB.

#define NCOL 1024
#define NROWIMG 1024
#define H2 1048576.0f
#define OMG2 6400.0f   // OMEGA^2

typedef float f4 __attribute__((ext_vector_type(4)));

// ---------------- hot path: 2 rows x 4 cols per thread, XCD-slab swizzle -----
__global__ __launch_bounds__(256) void helm_real8_xcd(
    const f4* __restrict__ x4,   // nk/4 vectors
    const f4* __restrict__ k4,
    f4* __restrict__ o4)
{
    // Swizzle: consecutive physical blocks go to XCDs round-robin (bid & 7).
    // Give XCD k the contiguous band range [k*512, (k+1)*512) = image k.
    const int bid  = blockIdx.x;                  // 0..4095
    const int vb   = ((bid & 7) << 9) | (bid >> 3);  // virtual band index
    const int t    = vb * 256 + threadIdx.x;      // virtual thread id
    const int cg   = t & 255;                     // column group (cols 4cg..+3)
    const int band = t >> 8;                      // 2-row band
    const long r0  = (long)band << 1;             // first output row
    const int  i0  = (int)(r0 & (NROWIMG - 1));   // row within image (even)

    const long base = r0 * 256 + cg;              // vector index of (r0, cg)

    // x rows r0-1 .. r0+2; bands never straddle images.
    const f4 a1 = x4[base];
    const f4 a2 = x4[base + 256];
    const f4 a0 = (i0 > 0)           ? x4[base - 256] : (f4)(0.f);
    const f4 a3 = (i0 < NROWIMG - 2) ? x4[base + 512] : (f4)(0.f);

    // kappa: single-use stream -> nontemporal (don't pollute L2 halo space).
    const f4 kk0 = __builtin_nontemporal_load(&k4[base]);
    const f4 kk1 = __builtin_nontemporal_load(&k4[base + 256]);

    // Edge neighbors for the two rows.
    const float* x = (const float*)x4;
    const long e0 = 4L * base;
    float lf0 = 0.f, lf1 = 0.f, rt0 = 0.f, rt1 = 0.f;
    if (cg > 0)   { lf0 = x[e0 - 1]; lf1 = x[e0 + 1024 - 1]; }
    if (cg < 255) { rt0 = x[e0 + 4]; rt1 = x[e0 + 1024 + 4]; }

    f4 o;
    // row r0: center a1, up a0, down a2
    o.x = (4.f*a1.x - a0.x - a2.x - lf0  - a1.y) * H2 - OMG2 * (kk0.x*kk0.x) * a1.x;
    o.y = (4.f*a1.y - a0.y - a2.y - a1.x - a1.z) * H2 - OMG2 * (kk0.y*kk0.y) * a1.y;
    o.z = (4.f*a1.z - a0.z - a2.z - a1.y - a1.w) * H2 - OMG2 * (kk0.z*kk0.z) * a1.z;
    o.w = (4.f*a1.w - a0.w - a2.w - a1.z - rt0 ) * H2 - OMG2 * (kk0.w*kk0.w) * a1.w;
    __builtin_nontemporal_store(o, &o4[base]);

    // row r0+1: center a2, up a1, down a3
    o.x = (4.f*a2.x - a1.x - a3.x - lf1  - a2.y) * H2 - OMG2 * (kk1.x*kk1.x) * a2.x;
    o.y = (4.f*a2.y - a1.y - a3.y - a2.x - a2.z) * H2 - OMG2 * (kk1.y*kk1.y) * a2.y;
    o.z = (4.f*a2.z - a1.z - a3.z - a2.y - a2.w) * H2 - OMG2 * (kk1.z*kk1.z) * a2.z;
    o.w = (4.f*a2.w - a1.w - a3.w - a2.z - rt1 ) * H2 - OMG2 * (kk1.w*kk1.w) * a2.w;
    __builtin_nontemporal_store(o, &o4[base + 256]);
}

// ---------------- safe fallback (proven correct rounds 2-7), any layout ------
__global__ __launch_bounds__(256) void helm_adapt(
    const float* __restrict__ xa,
    const float* __restrict__ xb,
    const float* __restrict__ kap,
    const float* __restrict__ gma,
    float* __restrict__ out,
    int nk, int world, int omode)
{
    const int e = blockIdx.x * blockDim.x + threadIdx.x;
    if (e >= nk) return;
    const int col = e & (NCOL - 1);
    const int row = e >> 10;
    const int i   = row & (NROWIMG - 1);

    float cr, ci;
    float ur = 0.f, ui = 0.f, dr = 0.f, di = 0.f;
    float lr = 0.f, li = 0.f, rr = 0.f, ri = 0.f;

    if (world == 0) {
        const float2* x2 = (const float2*)xa;
        float2 c = x2[e]; cr = c.x; ci = c.y;
        if (i > 0)          { float2 tv = x2[e - NCOL]; ur = tv.x; ui = tv.y; }
        if (i < NROWIMG - 1){ float2 tv = x2[e + NCOL]; dr = tv.x; di = tv.y; }
        if (col > 0)        { float2 tv = x2[e - 1];    lr = tv.x; li = tv.y; }
        if (col < NCOL - 1) { float2 tv = x2[e + 1];    rr = tv.x; ri = tv.y; }
    } else if (world == 1) {
        cr = xa[e]; ci = xb[e];
        if (i > 0)          { ur = xa[e - NCOL]; ui = xb[e - NCOL]; }
        if (i < NROWIMG - 1){ dr = xa[e + NCOL]; di = xb[e + NCOL]; }
        if (col > 0)        { lr = xa[e - 1];    li = xb[e - 1]; }
        if (col < NCOL - 1) { rr = xa[e + 1];    ri = xb[e + 1]; }
    } else {
        cr = xa[e]; ci = 0.f;
        if (i > 0)          ur = xa[e - NCOL];
        if (i < NROWIMG - 1) dr = xa[e + NCOL];
        if (col > 0)        lr = xa[e - 1];
        if (col < NCOL - 1) rr = xa[e + 1];
    }

    const float kk = kap[e];
    const float gg = gma[e];

    const float lapr = (4.f * cr - ur - dr - lr - rr) * H2;
    const float lapi = (4.f * ci - ui - di - li - ri) * H2;
    const float ks = kk * kk;
    const float hr = OMG2 * ks;
    const float hi = -80.0f * ks * gg;
    const float or_ = lapr - (hr * cr - hi * ci);
    const float oi_ = lapi - (hr * ci + hi * cr);

    if (omode == 0) {
        ((float2*)out)[e] = make_float2(or_, oi_);
    } else if (omode == 1) {
        out[e] = or_;
        out[nk + e] = oi_;
    } else {
        out[e] = or_;
    }
}

extern "C" void kernel_launch(void* const* d_in, const int* in_sizes, int n_in,
                              void* d_out, int out_size, void* d_ws, size_t ws_size,
                              hipStream_t stream) {
    const int nk = in_sizes[n_in - 2];            // kappa element count
    const float* kap = (const float*)d_in[n_in - 2];
    const float* gma = (const float*)d_in[n_in - 1];
    const float* xa  = (const float*)d_in[0];
    const float* xb  = nullptr;

    const int block = 256;

    // Hot path: real-only planes, 8M floats (proven rounds 5-7).
    if (n_in == 3 && in_sizes[0] == nk && out_size == nk &&
        nk == 8 * 1024 * 1024) {
        const int grid = nk / 8 / block;          // 4096 (512 bands per image)
        helm_real8_xcd<<<grid, block, 0, stream>>>(
            (const f4*)xa, (const f4*)kap, (f4*)d_out);
        return;
    }

    // Fallback: layout-adaptive, bounds-guarded (proven rounds 2-7).
    int world;
    if (n_in >= 4)                    { world = 1; xb = (const float*)d_in[1]; }
    else if (in_sizes[0] >= 2 * nk)   { world = 0; }
    else                              { world = 2; }

    int omode;
    if (out_size >= 2 * nk) omode = (world == 1) ? 1 : 0;
    else                    omode = 2;

    const int grid = (nk + block - 1) / block;
    helm_adapt<<<grid, block, 0, stream>>>(xa, xb, kap, gma, (float*)d_out,
                                           nk, world, omode);
}